// Round 14
// baseline (250.065 us; speedup 1.0000x reference)
//
#include <hip/hip_runtime.h>
#include <stdint.h>

typedef short bf16x4 __attribute__((ext_vector_type(4)));
typedef short bf16x8 __attribute__((ext_vector_type(8)));
typedef _Float16 f16x8 __attribute__((ext_vector_type(8)));
typedef float f32x4 __attribute__((ext_vector_type(4)));
typedef float f32x16 __attribute__((ext_vector_type(16)));
typedef unsigned int u32x4 __attribute__((ext_vector_type(4)));
typedef unsigned int u32x2 __attribute__((ext_vector_type(2)));

#if __has_builtin(__builtin_amdgcn_exp2f)
#define EXP2 __builtin_amdgcn_exp2f
#else
#define EXP2 exp2f
#endif

// ---------- helpers ----------
__device__ __forceinline__ short f2bf(float f) {  // RNE f32->bf16 (finite inputs)
  union { float f; uint32_t u; } v; v.f = f;
  uint32_t r = (v.u + 0x7fffu + ((v.u >> 16) & 1u)) >> 16;
  return (short)(uint16_t)r;
}

__device__ __forceinline__ unsigned cvtpk_bf16(float lo, float hi) {
  unsigned r;
  asm("v_cvt_pk_bf16_f32 %0, %1, %2" : "=v"(r) : "v"(lo), "v"(hi));
  return r;
}

// v_permlane32_swap_b32 via the BUILTIN (hazard-safe; round-5 verified).
#if __has_builtin(__builtin_amdgcn_permlane32_swap)
__device__ __forceinline__ void plane32_swap(unsigned& a, unsigned& b) {
  u32x2 r = __builtin_amdgcn_permlane32_swap(a, b, false, false);
  a = r[0]; b = r[1];
}
__device__ __forceinline__ float xhalf_max(float x) {
  unsigned xu = __builtin_bit_cast(unsigned, x);
  u32x2 r = __builtin_amdgcn_permlane32_swap(xu, xu, false, false);
  return fmaxf(__builtin_bit_cast(float, r[0]), __builtin_bit_cast(float, r[1]));
}
__device__ __forceinline__ float xhalf_sum(float x) {
  unsigned xu = __builtin_bit_cast(unsigned, x);
  u32x2 r = __builtin_amdgcn_permlane32_swap(xu, xu, false, false);
  return __builtin_bit_cast(float, r[0]) + __builtin_bit_cast(float, r[1]);
}
#else
__device__ __forceinline__ void plane32_swap(unsigned& a, unsigned& b) {
  asm("s_nop 1\n\tv_permlane32_swap_b32 %0, %1" : "+v"(a), "+v"(b));
}
__device__ __forceinline__ float xhalf_max(float x) { return fmaxf(x, __shfl_xor(x, 32, 64)); }
__device__ __forceinline__ float xhalf_sum(float x) { return x + __shfl_xor(x, 32, 64); }
#endif

__device__ __forceinline__ float fmax3(float a, float b, float c) {
  return fmaxf(fmaxf(a, b), c);  // clang fuses to v_max3_f32
}

__device__ __forceinline__ float tmax16(const f32x16& s) {
  float a0 = fmax3(s[0], s[1], s[2]);
  float a1 = fmax3(s[3], s[4], s[5]);
  float a2 = fmax3(s[6], s[7], s[8]);
  float a3 = fmax3(s[9], s[10], s[11]);
  float a4 = fmax3(s[12], s[13], s[14]);
  float b0 = fmax3(a0, a1, s[15]);
  float b1 = fmax3(a2, a3, a4);
  return fmaxf(b0, b1);
}
__device__ __forceinline__ float tsum16(const f32x16& s) {
  float a0 = (s[0] + s[1]) + (s[2] + s[3]);
  float a1 = (s[4] + s[5]) + (s[6] + s[7]);
  float a2 = (s[8] + s[9]) + (s[10] + s[11]);
  float a3 = (s[12] + s[13]) + (s[14] + s[15]);
  return (a0 + a1) + (a2 + a3);
}

__device__ __forceinline__ f32x16 zero16() {
  f32x16 z;
#pragma unroll
  for (int i = 0; i < 16; ++i) z[i] = 0.f;
  return z;
}

__device__ __forceinline__ void gld_lds16(const void* g, void* l) {
  __builtin_amdgcn_global_load_lds(
      (__attribute__((address_space(1))) const void*)g,
      (__attribute__((address_space(3))) void*)l, 16, 0, 0);
}

// ---------- RMSNorm + cast to bf16 ----------
__global__ __launch_bounds__(256) void k_rmsnorm(const float* __restrict__ x,
                                                 const float* __restrict__ wn,
                                                 short* __restrict__ xn) {
  const int row = blockIdx.x;      // 8192 rows
  const int t = threadIdx.x;       // 256 threads, 4 floats each
  const float4 v = reinterpret_cast<const float4*>(x + (size_t)row * 1024)[t];
  float ss = v.x * v.x + v.y * v.y + v.z * v.z + v.w * v.w;
#pragma unroll
  for (int m = 32; m >= 1; m >>= 1) ss += __shfl_xor(ss, m, 64);
  __shared__ float red[4];
  if ((t & 63) == 0) red[t >> 6] = ss;
  __syncthreads();
  const float tot = red[0] + red[1] + red[2] + red[3];
  const float rr = rsqrtf(tot * (1.0f / 1024.0f) + 1e-5f);
  const float4 g = reinterpret_cast<const float4*>(wn)[t];
  bf16x4 o;
  o[0] = f2bf(v.x * rr * g.x);
  o[1] = f2bf(v.y * rr * g.y);
  o[2] = f2bf(v.z * rr * g.z);
  o[3] = f2bf(v.w * rr * g.w);
  reinterpret_cast<bf16x4*>(xn + (size_t)row * 1024)[t] = o;
}

// ---------- casts ----------
__global__ __launch_bounds__(256) void k_cast_bf(const float* __restrict__ in,
                                                 short* __restrict__ out, int n4) {
  int i = blockIdx.x * 256 + threadIdx.x;
  if (i >= n4) return;
  float4 v = reinterpret_cast<const float4*>(in)[i];
  bf16x4 o;
  o[0] = f2bf(v.x); o[1] = f2bf(v.y); o[2] = f2bf(v.z); o[3] = f2bf(v.w);
  reinterpret_cast<bf16x4*>(out)[i] = o;
}

__global__ __launch_bounds__(256) void k_cast_f16(const float* __restrict__ in,
                                                  _Float16* __restrict__ out, int n4) {
  int i = blockIdx.x * 256 + threadIdx.x;
  if (i >= n4) return;
  float4 v = reinterpret_cast<const float4*>(in)[i];
  _Float16 o[4] = {(_Float16)v.x, (_Float16)v.y, (_Float16)v.z, (_Float16)v.w};
  reinterpret_cast<ulong1*>(out)[i] = *reinterpret_cast<ulong1*>(o);
}

// ---------- QKV GEMM v2: 256x256, BK=64, 8-phase counted-vmcnt pipeline ----------
// T2 (row-XOR LDS swizzle, both-sides involution), T3+T4 (8 phases, vmcnt
// never drained to 0 in the loop), T5 (setprio around MFMA clusters).
// 512 threads = 8 waves (2M x 4N); per-wave output 128x64; LDS 128KB =
// 2 dbuf x 2 half x (128 rows x 64 cols) x {A,B}. Per K-tile: 4 phases with
// {12,4,8,0} ds_read_b128 + exactly 1 half-tile stage (2 gld_lds) each.
// Stage schedule (iteration computes tiles t=2i in buf0, t+1 in buf1):
//   P1:B1h1(t+1) P2:A1h1(t+1) P3:B0h0(t+2) P4:B0h1(t+2)+vmcnt(4)
//   P5:A0h0(t+2) P6:A0h1(t+2) P7:B1h0(t+3) P8:A1h0(t+3)+vmcnt(4)
// Safety: a half is staged only >=1 barrier after its last reader's MFMA
// (lgkmcnt(0)-before-MFMA + barrier-after-MFMA certify reads complete);
// vmcnt(4) leaves exactly the 2 newest half-stages in flight. Tail stages
// clamp to tile 15 (junk overwrites only dead halves; never read).
// Epilogue: scatter to qb (scaled) / kfrag / vfrag (branch block-uniform).
__global__ __launch_bounds__(512, 2) void k_gemm_qkv(const short* __restrict__ A,
                                                     const short* __restrict__ B,
                                                     const float* __restrict__ bias,
                                                     short* __restrict__ qb,
                                                     short* __restrict__ kfrag,
                                                     short* __restrict__ vfrag) {
  __shared__ __align__(16) short LA[2][2][8192];  // 64KB [buf][half][128x64]
  __shared__ __align__(16) short LB[2][2][8192];  // 64KB
  const int t = threadIdx.x;
  const int w = t >> 6, l = t & 63;
  const int lm = l & 15, h = l >> 4, sw = lm & 7;
  // XCD swizzle: 384 blocks, 48 per XCD (384%8==0 -> bijective)
  const int orig = blockIdx.y * 12 + blockIdx.x;
  const int swzb = (orig & 7) * 48 + (orig >> 3);
  const long bn0 = (long)(swzb % 12) * 256;
  const long bm0 = (long)(swzb / 12) * 256;
  const int wAh = w >> 2;            // wave's A half (M rows 0-127 / 128-255)
  const int wBh = (w & 3) >> 1;      // wave's B half
  const int nb = (w & 1) * 64;       // N base within B half
  // staging: granule g = j*512+t -> (row=g>>3, col16=g&7); src col inverse-swizzled
  const int g0 = t, g1 = 512 + t;
  const int r0 = g0 >> 3, r1 = g1 >> 3;
  const int st0 = r0 * 1024 + ((g0 & 7) ^ (r0 & 7)) * 8;
  const int st1 = r1 * 1024 + ((g1 & 7) ^ (r1 & 7)) * 8;

  auto STAGE_A = [&](int buf, int half, int kt) {
    const short* base = A + (bm0 + half * 128) * 1024 + kt * 64;
    gld_lds16(base + st0, &LA[buf][half][g0 * 8]);
    gld_lds16(base + st1, &LA[buf][half][g1 * 8]);
  };
  auto STAGE_B = [&](int buf, int half, int kt) {
    const short* base = B + (bn0 + half * 128) * 1024 + kt * 64;
    gld_lds16(base + st0, &LB[buf][half][g0 * 8]);
    gld_lds16(base + st1, &LB[buf][half][g1 * 8]);
  };
  auto RD_A = [&](int buf, int mi, int ks) {
    const int row = mi * 16 + lm;
    return *reinterpret_cast<const bf16x8*>(
        &LA[buf][wAh][row * 64 + (((ks << 2) + h) ^ sw) * 8]);
  };
  auto RD_B = [&](int buf, int ni, int ks) {
    const int row = nb + ni * 16 + lm;
    return *reinterpret_cast<const bf16x8*>(
        &LB[buf][wBh][row * 64 + (((ks << 2) + h) ^ sw) * 8]);
  };

  f32x4 acc[8][4];
#pragma unroll
  for (int i = 0; i < 8; ++i)
#pragma unroll
    for (int j = 0; j < 4; ++j) acc[i][j] = (f32x4){0.f, 0.f, 0.f, 0.f};

  // prologue: tile0 fully (buf0) + tile1's Bh0/Ah0 (buf1); drain once
  STAGE_B(0, 0, 0); STAGE_B(0, 1, 0);
  STAGE_A(0, 0, 0); STAGE_A(0, 1, 0);
  STAGE_B(1, 0, 1); STAGE_A(1, 0, 1);
  asm volatile("s_waitcnt vmcnt(0)" ::: "memory");
  __builtin_amdgcn_s_barrier();

  bf16x8 af[4][2], bf0[4], bf1[4];
  auto MF = [&](bf16x8 (&afr)[4][2], bf16x8 (&bfr)[4], int ks, int mg) {
    __builtin_amdgcn_s_setprio(1);
#pragma unroll
    for (int mi = 0; mi < 4; ++mi)
#pragma unroll
      for (int ni = 0; ni < 4; ++ni)
        acc[mg + mi][ni] = __builtin_amdgcn_mfma_f32_16x16x32_bf16(
            afr[mi][ks], bfr[ni], acc[mg + mi][ni], 0, 0, 0);
    __builtin_amdgcn_s_setprio(0);
  };
#define QBAR __builtin_amdgcn_s_barrier()
#define QLGKM asm volatile("s_waitcnt lgkmcnt(0)" ::: "memory")
#define QVM4 asm volatile("s_waitcnt vmcnt(4)" ::: "memory")

  for (int i = 0; i < 8; ++i) {
    const int t2 = 2 * i;
    const int c1 = (t2 + 1 > 15) ? 15 : t2 + 1;
    const int c2 = (t2 + 2 > 15) ? 15 : t2 + 2;
    const int c3 = (t2 + 3 > 15) ? 15 : t2 + 3;
    // ---- tile t2 (buf0): P1-P4 ----
    // P1: A m0-3 both ksubs (8 rd) + B ks0 (4 rd); stage B1h1(t+1)
#pragma unroll
    for (int mi = 0; mi < 4; ++mi) { af[mi][0] = RD_A(0, mi, 0); af[mi][1] = RD_A(0, mi, 1); }
#pragma unroll
    for (int ni = 0; ni < 4; ++ni) bf0[ni] = RD_B(0, ni, 0);
    STAGE_B(1, 1, c1);
    QBAR; QLGKM; MF(af, bf0, 0, 0); QBAR;
    // P2: B ks1 (4 rd); stage A1h1(t+1)
#pragma unroll
    for (int ni = 0; ni < 4; ++ni) bf1[ni] = RD_B(0, ni, 1);
    STAGE_A(1, 1, c1);
    QBAR; QLGKM; MF(af, bf1, 1, 0); QBAR;
    // P3: A m4-7 both ksubs (8 rd); stage B0h0(t+2)
#pragma unroll
    for (int mi = 0; mi < 4; ++mi) { af[mi][0] = RD_A(0, mi + 4, 0); af[mi][1] = RD_A(0, mi + 4, 1); }
    STAGE_B(0, 0, c2);
    QBAR; QLGKM; MF(af, bf0, 0, 4); QBAR;
    // P4: no reads; stage B0h1(t+2); counted vmcnt
    STAGE_B(0, 1, c2);
    QVM4;
    QBAR; QLGKM; MF(af, bf1, 1, 4); QBAR;
    // ---- tile t2+1 (buf1): P5-P8 ----
    // P5
#pragma unroll
    for (int mi = 0; mi < 4; ++mi) { af[mi][0] = RD_A(1, mi, 0); af[mi][1] = RD_A(1, mi, 1); }
#pragma unroll
    for (int ni = 0; ni < 4; ++ni) bf0[ni] = RD_B(1, ni, 0);
    STAGE_A(0, 0, c2);
    QBAR; QLGKM; MF(af, bf0, 0, 0); QBAR;
    // P6
#pragma unroll
    for (int ni = 0; ni < 4; ++ni) bf1[ni] = RD_B(1, ni, 1);
    STAGE_A(0, 1, c2);
    QBAR; QLGKM; MF(af, bf1, 1, 0); QBAR;
    // P7
#pragma unroll
    for (int mi = 0; mi < 4; ++mi) { af[mi][0] = RD_A(1, mi + 4, 0); af[mi][1] = RD_A(1, mi + 4, 1); }
    STAGE_B(1, 0, c3);
    QBAR; QLGKM; MF(af, bf0, 0, 4); QBAR;
    // P8
    STAGE_A(1, 0, c3);
    QVM4;
    QBAR; QLGKM; MF(af, bf1, 1, 4); QBAR;
  }

  // epilogue: scatter (branch block-uniform: bn0 spans one 1024-col group)
  const int which = (int)(bn0 >> 10);
  const long mbase = bm0 + (long)(w >> 2) * 128;
  const int colbase = (int)bn0 + (w & 3) * 64;
#pragma unroll
  for (int ni = 0; ni < 4; ++ni) {
    const int ncol = colbase + ni * 16 + lm;
    const float bv = bias[ncol];
    const int e = ncol & 1023;
    const int hd = e >> 6, d = e & 63;
#pragma unroll
    for (int mi = 0; mi < 8; ++mi) {
#pragma unroll
      for (int r = 0; r < 4; ++r) {
        const long mrow = mbase + mi * 16 + h * 4 + r;
        const float val = acc[mi][ni][r] + bv;
        const long bh = (mrow >> 11) * 16 + hd;
        const int seq = (int)(mrow & 2047);
        if (which == 0) {
          qb[(bh * 2048 + seq) * 64 + d] = f2bf(val * 0.18033688011112042f);
        } else if (which == 1) {
          const long off = ((bh * 64 + (seq >> 5)) * 4 + (d >> 4)) * 512 +
                           ((seq & 31) | (((d >> 3) & 1) << 5)) * 8 + (d & 7);
          kfrag[off] = f2bf(val);
        } else {
          const long off = (((bh * 64 + (seq >> 5)) * 2 + (d >> 5)) * 2 +
                            ((seq >> 4) & 1)) * 512 +
                           ((d & 31) | (((seq >> 3) & 1) << 5)) * 8 + (seq & 7);
          vfrag[off] = f2bf(val);
        }
      }
    }
  }
}

// ---------- out-proj GEMM (fp16 inputs for precision, fp32 out) ----------
__global__ __launch_bounds__(256) void k_gemm_out(const _Float16* __restrict__ A,
                                                  const _Float16* __restrict__ B,
                                                  const float* __restrict__ bias,
                                                  float* __restrict__ outp) {
  __shared__ __align__(16) _Float16 As[128 * 32];
  __shared__ __align__(16) _Float16 Bs[128 * 32];
  const int t = threadIdx.x;
  // T1: nwg = 8*64 = 512, 512%8==0
  const int orig = blockIdx.y * 8 + blockIdx.x;
  const int swz = (orig & 7) * 64 + (orig >> 3);
  const long bn0 = (long)(swz % 8) * 128;
  const long bm0 = (long)(swz / 8) * 128;
  const int w = t >> 6, l = t & 63;
  const int wr = (w >> 1) * 64, wc = (w & 1) * 64;
  const int lm = l & 15, h = l >> 4;
  f32x4 acc[4][4];
#pragma unroll
  for (int i = 0; i < 4; ++i)
#pragma unroll
    for (int j = 0; j < 4; ++j) acc[i][j] = (f32x4){0.f, 0.f, 0.f, 0.f};
  const int srow = t >> 2, scol = (t & 3) * 8;
  const _Float16* Ag = A + (bm0 + srow) * 1024 + scol;
  const _Float16* Bg = B + (bn0 + srow) * 1024 + scol;
  _Float16* AsP = As + t * 8;
  _Float16* BsP = Bs + t * 8;
  for (int kt = 0; kt < 32; ++kt) {
    const int k0 = kt << 5;
    gld_lds16(Ag + k0, AsP);
    gld_lds16(Ag + k0 + 64 * 1024, AsP + 2048);
    gld_lds16(Bg + k0, BsP);
    gld_lds16(Bg + k0 + 64 * 1024, BsP + 2048);
    __syncthreads();
    f16x8 af[4], bfr[4];
#pragma unroll
    for (int mi = 0; mi < 4; ++mi)
      af[mi] = *reinterpret_cast<const f16x8*>(As + (wr + mi * 16 + lm) * 32 + h * 8);
#pragma unroll
    for (int ni = 0; ni < 4; ++ni)
      bfr[ni] = *reinterpret_cast<const f16x8*>(Bs + (wc + ni * 16 + lm) * 32 + h * 8);
    __builtin_amdgcn_s_setprio(1);
#pragma unroll
    for (int mi = 0; mi < 4; ++mi)
#pragma unroll
      for (int ni = 0; ni < 4; ++ni)
        acc[mi][ni] = __builtin_amdgcn_mfma_f32_16x16x32_f16(af[mi], bfr[ni], acc[mi][ni], 0, 0, 0);
    __builtin_amdgcn_s_setprio(0);
    __syncthreads();
  }
#pragma unroll
  for (int ni = 0; ni < 4; ++ni) {
    const int ncol = (int)bn0 + wc + ni * 16 + lm;
    const float bv = bias[ncol];
#pragma unroll
    for (int mi = 0; mi < 4; ++mi) {
#pragma unroll
      for (int r = 0; r < 4; ++r) {
        const long mrow = bm0 + wr + mi * 16 + h * 4 + r;
        outp[mrow * 1024 + ncol] = acc[mi][ni][r] + bv;
      }
    }
  }
}

// ---------- flash attention v11 (round-13 verified, unchanged) ----------
__global__ __launch_bounds__(256, 4) void k_attn(const short* __restrict__ q,
                                                 const short* __restrict__ kfrag,
                                                 const short* __restrict__ vfrag,
                                                 _Float16* __restrict__ o) {
  const int orig = blockIdx.y * 16 + blockIdx.x;
  const int work = (orig & 7) * 128 + (orig >> 3);
  const int bh = work >> 4;    // 64 heads
  const int qt = work & 15;    // 16 q-tiles of 128 rows
  const int t = threadIdx.x;
  const int w = t >> 6, l = t & 63;
  const int lq = l & 31, hh = l >> 5;
  const int qrow = qt * 128 + w * 32 + lq;

  bf16x8 qf[4];
  const short* qp = q + ((size_t)(bh * 2048 + qrow)) * 64 + hh * 8;
#pragma unroll
  for (int db = 0; db < 4; ++db)
    qf[db] = *reinterpret_cast<const bf16x8*>(qp + db * 16);

  const short* kfb = kfrag + (size_t)bh * 64 * 2048 + l * 8;
  const short* vfb = vfrag + (size_t)bh * 64 * 2048 + l * 8;

  f32x16 oa0 = zero16(), oa1 = zero16();
  float mr = -1e30f, lr = 0.f;

  auto LOADK = [&](bf16x8* kf, int kt) {
    const short* kp = kfb + (size_t)kt * 2048;
#pragma unroll
    for (int db = 0; db < 4; ++db)
      kf[db] = *reinterpret_cast<const bf16x8*>(kp + db * 512);
  };
  auto LOADV = [&](bf16x8* vf, int kt) {
    const short* vp = vfb + (size_t)kt * 2048;
#pragma unroll
    for (int i = 0; i < 4; ++i)
      vf[i] = *reinterpret_cast<const bf16x8*>(vp + i * 512);
  };

  auto COMPUTE = [&](const bf16x8* kf, const bf16x8* vf) {
    f32x16 s = zero16();
    __builtin_amdgcn_s_setprio(1);
#pragma unroll
    for (int db = 0; db < 4; ++db)
      s = __builtin_amdgcn_mfma_f32_32x32x16_bf16(kf[db], qf[db], s, 0, 0, 0);
    __builtin_amdgcn_s_setprio(0);
    float tm = xhalf_max(tmax16(s));
    if (!__all(tm <= mr + 8.f)) {
      const float mn = fmaxf(mr, tm);
      const float c = EXP2(mr - mn);
      lr *= c;
#pragma unroll
      for (int r = 0; r < 16; ++r) { oa0[r] *= c; oa1[r] *= c; }
      mr = mn;
    }
#pragma unroll
    for (int r = 0; r < 16; ++r) s[r] = EXP2(s[r] - mr);
    lr += tsum16(s);
    __builtin_amdgcn_s_setprio(1);
#pragma unroll
    for (int kg = 0; kg < 2; ++kg) {
      const int b0 = kg * 8;
      unsigned w0 = cvtpk_bf16(s[b0 + 0], s[b0 + 1]);
      unsigned w1 = cvtpk_bf16(s[b0 + 2], s[b0 + 3]);
      unsigned w2 = cvtpk_bf16(s[b0 + 4], s[b0 + 5]);
      unsigned w3 = cvtpk_bf16(s[b0 + 6], s[b0 + 7]);
      plane32_swap(w0, w2);
      plane32_swap(w1, w3);
      u32x4 pw = {w0, w1, w2, w3};
      bf16x8 pf = *reinterpret_cast<bf16x8*>(&pw);
      oa0 = __builtin_amdgcn_mfma_f32_32x32x16_bf16(vf[0 * 2 + kg], pf, oa0, 0, 0, 0);
      oa1 = __builtin_amdgcn_mfma_f32_32x32x16_bf16(vf[1 * 2 + kg], pf, oa1, 0, 0, 0);
    }
    __builtin_amdgcn_s_setprio(0);
  };

  bf16x8 kfA[4], kfB[4], vf[4];
  LOADK(kfA, 0);
  for (int kt = 0; kt < 64; kt += 2) {
    LOADK(kfB, kt + 1);
    LOADV(vf, kt);
    COMPUTE(kfA, vf);
    int k2 = kt + 2; if (k2 > 63) k2 = 63;
    LOADK(kfA, k2);
    LOADV(vf, kt + 1);
    COMPUTE(kfB, vf);
  }
  const float inv = 1.0f / xhalf_sum(lr);
  const int b = bh >> 4, hd = bh & 15;
  _Float16* ob = o + ((size_t)(b * 2048 + qrow)) * 1024 + hd * 64;
#pragma unroll
  for (int r2 = 0; r2 < 16; ++r2) {
    const int d0 = (r2 & 3) + 8 * (r2 >> 2) + 4 * hh;  // 32x32 C layout
    ob[d0] = (_Float16)(oa0[r2] * inv);
    ob[d0 + 32] = (_Float16)(oa1[r2] * inv);
  }
}

// ---------- launch ----------
extern "C" void kernel_launch(void* const* d_in, const int* in_sizes, int n_in,
                              void* d_out, int out_size, void* d_ws, size_t ws_size,
                              hipStream_t stream) {
  const float* x = (const float*)d_in[0];
  const float* w_in = (const float*)d_in[1];
  const float* b_in = (const float*)d_in[2];
  const float* w_norm = (const float*)d_in[3];
  const float* w_out = (const float*)d_in[4];
  const float* b_out = (const float*)d_in[5];
  float* out = (float*)d_out;
  char* ws = (char*)d_ws;
  short* xn = (short*)(ws);                       // 16 MB [8192][1024] bf16
  short* win_b = (short*)(ws + 16777216);         // 6 MB  [3072][1024] bf16
  _Float16* wout_h = (_Float16*)(ws + 23068672);  // 2 MB  [1024][1024] f16
  short* qb = (short*)(ws + 25165824);            // 16 MB [BH][S][64] bf16
  short* kfrag = (short*)(ws + 41943040);         // 16 MB fragment-ordered K
  short* vfrag = (short*)(ws + 58720256);         // 16 MB fragment-ordered V
  _Float16* ob = (_Float16*)(ws + 75497472);      // 16 MB attn out [B][S][1024] f16

  k_cast_bf<<<3072, 256, 0, stream>>>(w_in, win_b, 786432);
  k_cast_f16<<<1024, 256, 0, stream>>>(w_out, wout_h, 262144);
  k_rmsnorm<<<8192, 256, 0, stream>>>(x, w_norm, xn);
  k_gemm_qkv<<<dim3(12, 32), 512, 0, stream>>>(xn, win_b, b_in, qb, kfrag, vfrag);
  k_attn<<<dim3(16, 64), 256, 0, stream>>>(qb, kfrag, vfrag, ob);
  k_gemm_out<<<dim3(8, 64), 256, 0, stream>>>(ob, wout_h, b_out, out);
}

// Round 15
// 231.309 us; speedup vs baseline: 1.0811x; 1.0811x over previous
//
#include <hip/hip_runtime.h>
#include <stdint.h>

typedef short bf16x4 __attribute__((ext_vector_type(4)));
typedef short bf16x8 __attribute__((ext_vector_type(8)));
typedef _Float16 f16x8 __attribute__((ext_vector_type(8)));
typedef float f32x4 __attribute__((ext_vector_type(4)));
typedef float f32x16 __attribute__((ext_vector_type(16)));
typedef unsigned int u32x4 __attribute__((ext_vector_type(4)));
typedef unsigned int u32x2 __attribute__((ext_vector_type(2)));

#if __has_builtin(__builtin_amdgcn_exp2f)
#define EXP2 __builtin_amdgcn_exp2f
#else
#define EXP2 exp2f
#endif

// ---------- helpers ----------
__device__ __forceinline__ short f2bf(float f) {  // RNE f32->bf16 (finite inputs)
  union { float f; uint32_t u; } v; v.f = f;
  uint32_t r = (v.u + 0x7fffu + ((v.u >> 16) & 1u)) >> 16;
  return (short)(uint16_t)r;
}

__device__ __forceinline__ unsigned cvtpk_bf16(float lo, float hi) {
  unsigned r;
  asm("v_cvt_pk_bf16_f32 %0, %1, %2" : "=v"(r) : "v"(lo), "v"(hi));
  return r;
}

// v_permlane32_swap_b32 via the BUILTIN (hazard-safe; round-5 verified).
#if __has_builtin(__builtin_amdgcn_permlane32_swap)
__device__ __forceinline__ void plane32_swap(unsigned& a, unsigned& b) {
  u32x2 r = __builtin_amdgcn_permlane32_swap(a, b, false, false);
  a = r[0]; b = r[1];
}
__device__ __forceinline__ float xhalf_max(float x) {
  unsigned xu = __builtin_bit_cast(unsigned, x);
  u32x2 r = __builtin_amdgcn_permlane32_swap(xu, xu, false, false);
  return fmaxf(__builtin_bit_cast(float, r[0]), __builtin_bit_cast(float, r[1]));
}
__device__ __forceinline__ float xhalf_sum(float x) {
  unsigned xu = __builtin_bit_cast(unsigned, x);
  u32x2 r = __builtin_amdgcn_permlane32_swap(xu, xu, false, false);
  return __builtin_bit_cast(float, r[0]) + __builtin_bit_cast(float, r[1]);
}
#else
__device__ __forceinline__ void plane32_swap(unsigned& a, unsigned& b) {
  asm("s_nop 1\n\tv_permlane32_swap_b32 %0, %1" : "+v"(a), "+v"(b));
}
__device__ __forceinline__ float xhalf_max(float x) { return fmaxf(x, __shfl_xor(x, 32, 64)); }
__device__ __forceinline__ float xhalf_sum(float x) { return x + __shfl_xor(x, 32, 64); }
#endif

__device__ __forceinline__ float fmax3(float a, float b, float c) {
  return fmaxf(fmaxf(a, b), c);  // clang fuses to v_max3_f32
}

__device__ __forceinline__ float tmax16(const f32x16& s) {
  float a0 = fmax3(s[0], s[1], s[2]);
  float a1 = fmax3(s[3], s[4], s[5]);
  float a2 = fmax3(s[6], s[7], s[8]);
  float a3 = fmax3(s[9], s[10], s[11]);
  float a4 = fmax3(s[12], s[13], s[14]);
  float b0 = fmax3(a0, a1, s[15]);
  float b1 = fmax3(a2, a3, a4);
  return fmaxf(b0, b1);
}
__device__ __forceinline__ float tsum16(const f32x16& s) {
  float a0 = (s[0] + s[1]) + (s[2] + s[3]);
  float a1 = (s[4] + s[5]) + (s[6] + s[7]);
  float a2 = (s[8] + s[9]) + (s[10] + s[11]);
  float a3 = (s[12] + s[13]) + (s[14] + s[15]);
  return (a0 + a1) + (a2 + a3);
}

__device__ __forceinline__ f32x16 zero16() {
  f32x16 z;
#pragma unroll
  for (int i = 0; i < 16; ++i) z[i] = 0.f;
  return z;
}

__device__ __forceinline__ void gld_lds16(const void* g, void* l) {
  __builtin_amdgcn_global_load_lds(
      (__attribute__((address_space(1))) const void*)g,
      (__attribute__((address_space(3))) void*)l, 16, 0, 0);
}

// ---------- RMSNorm + cast to bf16 ----------
__global__ __launch_bounds__(256) void k_rmsnorm(const float* __restrict__ x,
                                                 const float* __restrict__ wn,
                                                 short* __restrict__ xn) {
  const int row = blockIdx.x;      // 8192 rows
  const int t = threadIdx.x;       // 256 threads, 4 floats each
  const float4 v = reinterpret_cast<const float4*>(x + (size_t)row * 1024)[t];
  float ss = v.x * v.x + v.y * v.y + v.z * v.z + v.w * v.w;
#pragma unroll
  for (int m = 32; m >= 1; m >>= 1) ss += __shfl_xor(ss, m, 64);
  __shared__ float red[4];
  if ((t & 63) == 0) red[t >> 6] = ss;
  __syncthreads();
  const float tot = red[0] + red[1] + red[2] + red[3];
  const float rr = rsqrtf(tot * (1.0f / 1024.0f) + 1e-5f);
  const float4 g = reinterpret_cast<const float4*>(wn)[t];
  bf16x4 o;
  o[0] = f2bf(v.x * rr * g.x);
  o[1] = f2bf(v.y * rr * g.y);
  o[2] = f2bf(v.z * rr * g.z);
  o[3] = f2bf(v.w * rr * g.w);
  reinterpret_cast<bf16x4*>(xn + (size_t)row * 1024)[t] = o;
}

// ---------- casts ----------
__global__ __launch_bounds__(256) void k_cast_bf(const float* __restrict__ in,
                                                 short* __restrict__ out, int n4) {
  int i = blockIdx.x * 256 + threadIdx.x;
  if (i >= n4) return;
  float4 v = reinterpret_cast<const float4*>(in)[i];
  bf16x4 o;
  o[0] = f2bf(v.x); o[1] = f2bf(v.y); o[2] = f2bf(v.z); o[3] = f2bf(v.w);
  reinterpret_cast<bf16x4*>(out)[i] = o;
}

__global__ __launch_bounds__(256) void k_cast_f16(const float* __restrict__ in,
                                                  _Float16* __restrict__ out, int n4) {
  int i = blockIdx.x * 256 + threadIdx.x;
  if (i >= n4) return;
  float4 v = reinterpret_cast<const float4*>(in)[i];
  _Float16 o[4] = {(_Float16)v.x, (_Float16)v.y, (_Float16)v.z, (_Float16)v.w};
  reinterpret_cast<ulong1*>(out)[i] = *reinterpret_cast<ulong1*>(o);
}

// ---------- QKV GEMM (round-13 m97 structure, 128x128xBK32, T1 XCD swizzle) ----------
// Epilogue scatters Q to [BH][S][64] (scaled for exp2-softmax) and K/V
// directly into MFMA-FRAGMENT order so attention loads are lane-linear.
__global__ __launch_bounds__(256) void k_gemm_qkv(const short* __restrict__ A,
                                                  const short* __restrict__ B,
                                                  const float* __restrict__ bias,
                                                  short* __restrict__ qb,
                                                  short* __restrict__ kfrag,
                                                  short* __restrict__ vfrag) {
  __shared__ __align__(16) short As[128 * 32];
  __shared__ __align__(16) short Bs[128 * 32];
  const int t = threadIdx.x;
  // T1: XCD-aware remap (nwg = 24*64 = 1536, 1536%8==0)
  const int orig = blockIdx.y * 24 + blockIdx.x;
  const int swz = (orig & 7) * 192 + (orig >> 3);
  const long bn0 = (long)(swz % 24) * 128;
  const long bm0 = (long)(swz / 24) * 128;
  const int w = t >> 6, l = t & 63;
  const int wr = (w >> 1) * 64, wc = (w & 1) * 64;
  const int lm = l & 15, h = l >> 4;
  f32x4 acc[4][4];
#pragma unroll
  for (int i = 0; i < 4; ++i)
#pragma unroll
    for (int j = 0; j < 4; ++j) acc[i][j] = (f32x4){0.f, 0.f, 0.f, 0.f};
  const int srow = t >> 2, scol = (t & 3) * 8;
  const short* Ag = A + (bm0 + srow) * 1024 + scol;
  const short* Bg = B + (bn0 + srow) * 1024 + scol;
  short* AsP = As + t * 8;
  short* BsP = Bs + t * 8;
  for (int kt = 0; kt < 32; ++kt) {
    const int k0 = kt << 5;
    gld_lds16(Ag + k0, AsP);
    gld_lds16(Ag + k0 + 64 * 1024, AsP + 2048);
    gld_lds16(Bg + k0, BsP);
    gld_lds16(Bg + k0 + 64 * 1024, BsP + 2048);
    __syncthreads();
    bf16x8 af[4], bfr[4];
#pragma unroll
    for (int mi = 0; mi < 4; ++mi)
      af[mi] = *reinterpret_cast<const bf16x8*>(As + (wr + mi * 16 + lm) * 32 + h * 8);
#pragma unroll
    for (int ni = 0; ni < 4; ++ni)
      bfr[ni] = *reinterpret_cast<const bf16x8*>(Bs + (wc + ni * 16 + lm) * 32 + h * 8);
    __builtin_amdgcn_s_setprio(1);
#pragma unroll
    for (int mi = 0; mi < 4; ++mi)
#pragma unroll
      for (int ni = 0; ni < 4; ++ni)
        acc[mi][ni] = __builtin_amdgcn_mfma_f32_16x16x32_bf16(af[mi], bfr[ni], acc[mi][ni], 0, 0, 0);
    __builtin_amdgcn_s_setprio(0);
    __syncthreads();
  }
#pragma unroll
  for (int ni = 0; ni < 4; ++ni) {
    const int ncol = (int)bn0 + wc + ni * 16 + lm;
    const float bv = bias[ncol];
    const int which = ncol >> 10;
    const int e = ncol & 1023;
    const int hd = e >> 6, d = e & 63;
#pragma unroll
    for (int mi = 0; mi < 4; ++mi) {
#pragma unroll
      for (int r = 0; r < 4; ++r) {
        const long mrow = bm0 + wr + mi * 16 + h * 4 + r;
        const float val = acc[mi][ni][r] + bv;
        const long bh = (mrow >> 11) * 16 + hd;
        const int seq = (int)(mrow & 2047);
        if (which == 0) {
          const long off = (bh * 2048 + seq) * 64 + d;
          qb[off] = f2bf(val * 0.18033688011112042f);  // 0.125*log2(e)
        } else if (which == 1) {
          const long off = ((bh * 64 + (seq >> 5)) * 4 + (d >> 4)) * 512 +
                           ((seq & 31) | (((d >> 3) & 1) << 5)) * 8 + (d & 7);
          kfrag[off] = f2bf(val);
        } else {
          const long off = (((bh * 64 + (seq >> 5)) * 2 + (d >> 5)) * 2 +
                            ((seq >> 4) & 1)) * 512 +
                           ((d & 31) | (((seq >> 3) & 1) << 5)) * 8 + (seq & 7);
          vfrag[off] = f2bf(val);
        }
      }
    }
  }
}

// ---------- out-proj GEMM (fp16 inputs for precision, fp32 out) ----------
__global__ __launch_bounds__(256) void k_gemm_out(const _Float16* __restrict__ A,
                                                  const _Float16* __restrict__ B,
                                                  const float* __restrict__ bias,
                                                  float* __restrict__ outp) {
  __shared__ __align__(16) _Float16 As[128 * 32];
  __shared__ __align__(16) _Float16 Bs[128 * 32];
  const int t = threadIdx.x;
  // T1: nwg = 8*64 = 512, 512%8==0
  const int orig = blockIdx.y * 8 + blockIdx.x;
  const int swz = (orig & 7) * 64 + (orig >> 3);
  const long bn0 = (long)(swz % 8) * 128;
  const long bm0 = (long)(swz / 8) * 128;
  const int w = t >> 6, l = t & 63;
  const int wr = (w >> 1) * 64, wc = (w & 1) * 64;
  const int lm = l & 15, h = l >> 4;
  f32x4 acc[4][4];
#pragma unroll
  for (int i = 0; i < 4; ++i)
#pragma unroll
    for (int j = 0; j < 4; ++j) acc[i][j] = (f32x4){0.f, 0.f, 0.f, 0.f};
  const int srow = t >> 2, scol = (t & 3) * 8;
  const _Float16* Ag = A + (bm0 + srow) * 1024 + scol;
  const _Float16* Bg = B + (bn0 + srow) * 1024 + scol;
  _Float16* AsP = As + t * 8;
  _Float16* BsP = Bs + t * 8;
  for (int kt = 0; kt < 32; ++kt) {
    const int k0 = kt << 5;
    gld_lds16(Ag + k0, AsP);
    gld_lds16(Ag + k0 + 64 * 1024, AsP + 2048);
    gld_lds16(Bg + k0, BsP);
    gld_lds16(Bg + k0 + 64 * 1024, BsP + 2048);
    __syncthreads();
    f16x8 af[4], bfr[4];
#pragma unroll
    for (int mi = 0; mi < 4; ++mi)
      af[mi] = *reinterpret_cast<const f16x8*>(As + (wr + mi * 16 + lm) * 32 + h * 8);
#pragma unroll
    for (int ni = 0; ni < 4; ++ni)
      bfr[ni] = *reinterpret_cast<const f16x8*>(Bs + (wc + ni * 16 + lm) * 32 + h * 8);
    __builtin_amdgcn_s_setprio(1);
#pragma unroll
    for (int mi = 0; mi < 4; ++mi)
#pragma unroll
      for (int ni = 0; ni < 4; ++ni)
        acc[mi][ni] = __builtin_amdgcn_mfma_f32_16x16x32_f16(af[mi], bfr[ni], acc[mi][ni], 0, 0, 0);
    __builtin_amdgcn_s_setprio(0);
    __syncthreads();
  }
#pragma unroll
  for (int ni = 0; ni < 4; ++ni) {
    const int ncol = (int)bn0 + wc + ni * 16 + lm;
    const float bv = bias[ncol];
#pragma unroll
    for (int mi = 0; mi < 4; ++mi) {
#pragma unroll
      for (int r = 0; r < 4; ++r) {
        const long mrow = bm0 + wr + mi * 16 + h * 4 + r;
        outp[mrow * 1024 + ncol] = acc[mi][ni][r] + bv;
      }
    }
  }
}

// ---------- flash attention v12: slim (<=128 unified regs), JIT loads ----------
// Round-12/13 lesson: occupancy quantizes at UNIFIED (VGPR+AGPR) 64/128/256.
// v11's K ping-pong kept unified ~150+ -> 2 waves/SIMD forever. v12 drops the
// ping-pong: K and V fragments loaded just-in-time each iteration (unroll 1),
// peak live state ~110-120 unified (acc 32 AGPR + qf 16 + kf 16 + vf 16 +
// s 16 + addressing) -> 4 waves/SIMD at __launch_bounds__(256,4). JIT load
// latency (L2-resident fragments, ~250cy) is covered by the doubled TLP --
// round 10's JIT failure was at 2 waves/SIMD, not a property of JIT itself.
__global__ __launch_bounds__(256, 4) void k_attn(const short* __restrict__ q,
                                                 const short* __restrict__ kfrag,
                                                 const short* __restrict__ vfrag,
                                                 _Float16* __restrict__ o) {
  // XCD swizzle: 1024 blocks = 8 x 128; each XCD owns 8 whole heads (4MB L2)
  const int orig = blockIdx.y * 16 + blockIdx.x;
  const int work = (orig & 7) * 128 + (orig >> 3);
  const int bh = work >> 4;    // 64 heads
  const int qt = work & 15;    // 16 q-tiles of 128 rows
  const int t = threadIdx.x;
  const int w = t >> 6, l = t & 63;
  const int lq = l & 31, hh = l >> 5;
  const int qrow = qt * 128 + w * 32 + lq;

  // Q fragments: qf[db] = Q[qrow][db*16 + hh*8 .. +8]
  bf16x8 qf[4];
  const short* qp = q + ((size_t)(bh * 2048 + qrow)) * 64 + hh * 8;
#pragma unroll
  for (int db = 0; db < 4; ++db)
    qf[db] = *reinterpret_cast<const bf16x8*>(qp + db * 16);

  // fragment-ordered K/V bases (lane-linear: + l*8 shorts; tile = 2048 shorts)
  const short* kfb = kfrag + (size_t)bh * 64 * 2048 + l * 8;
  const short* vfb = vfrag + (size_t)bh * 64 * 2048 + l * 8;

  f32x16 oa0 = zero16(), oa1 = zero16();  // dt=0,1 (d = lq, 32+lq)
  float mr = -1e30f, lr = 0.f;

#pragma unroll 1
  for (int kt = 0; kt < 64; ++kt) {
    bf16x8 kf[4], vf[4];
    const short* kp = kfb + (size_t)kt * 2048;
    const short* vp = vfb + (size_t)kt * 2048;
#pragma unroll
    for (int db = 0; db < 4; ++db)
      kf[db] = *reinterpret_cast<const bf16x8*>(kp + db * 512);
#pragma unroll
    for (int i = 0; i < 4; ++i)
      vf[i] = *reinterpret_cast<const bf16x8*>(vp + i * 512);

    f32x16 s = zero16();  // 32 keys x 32 q, q-col = lq
    __builtin_amdgcn_s_setprio(1);
#pragma unroll
    for (int db = 0; db < 4; ++db)
      s = __builtin_amdgcn_mfma_f32_32x32x16_bf16(kf[db], qf[db], s, 0, 0, 0);
    __builtin_amdgcn_s_setprio(0);
    float tm = xhalf_max(tmax16(s));
    // defer-max rescale (log2 domain, THR=8 => P <= 256)
    if (!__all(tm <= mr + 8.f)) {
      const float mn = fmaxf(mr, tm);
      const float c = EXP2(mr - mn);
      lr *= c;
#pragma unroll
      for (int r = 0; r < 16; ++r) { oa0[r] *= c; oa1[r] *= c; }
      mr = mn;
    }
#pragma unroll
    for (int r = 0; r < 16; ++r) s[r] = EXP2(s[r] - mr);
    lr += tsum16(s);  // per-half-lane partial; xhalf_sum'd at the end
    __builtin_amdgcn_s_setprio(1);
#pragma unroll
    for (int kg = 0; kg < 2; ++kg) {
      const int b0 = kg * 8;
      unsigned w0 = cvtpk_bf16(s[b0 + 0], s[b0 + 1]);
      unsigned w1 = cvtpk_bf16(s[b0 + 2], s[b0 + 3]);
      unsigned w2 = cvtpk_bf16(s[b0 + 4], s[b0 + 5]);
      unsigned w3 = cvtpk_bf16(s[b0 + 6], s[b0 + 7]);
      plane32_swap(w0, w2);
      plane32_swap(w1, w3);
      u32x4 pw = {w0, w1, w2, w3};
      bf16x8 pf = *reinterpret_cast<bf16x8*>(&pw);
      oa0 = __builtin_amdgcn_mfma_f32_32x32x16_bf16(vf[0 * 2 + kg], pf, oa0, 0, 0, 0);
      oa1 = __builtin_amdgcn_mfma_f32_32x32x16_bf16(vf[1 * 2 + kg], pf, oa1, 0, 0, 0);
    }
    __builtin_amdgcn_s_setprio(0);
  }
  const float inv = 1.0f / xhalf_sum(lr);
  const int b = bh >> 4, hd = bh & 15;
  _Float16* ob = o + ((size_t)(b * 2048 + qrow)) * 1024 + hd * 64;
#pragma unroll
  for (int r2 = 0; r2 < 16; ++r2) {
    const int d0 = (r2 & 3) + 8 * (r2 >> 2) + 4 * hh;  // 32x32 C layout
    ob[d0] = (_Float16)(oa0[r2] * inv);
    ob[d0 + 32] = (_Float16)(oa1[r2] * inv);
  }
}

// ---------- launch ----------
extern "C" void kernel_launch(void* const* d_in, const int* in_sizes, int n_in,
                              void* d_out, int out_size, void* d_ws, size_t ws_size,
                              hipStream_t stream) {
  const float* x = (const float*)d_in[0];
  const float* w_in = (const float*)d_in[1];
  const float* b_in = (const float*)d_in[2];
  const float* w_norm = (const float*)d_in[3];
  const float* w_out = (const float*)d_in[4];
  const float* b_out = (const float*)d_in[5];
  float* out = (float*)d_out;
  char* ws = (char*)d_ws;
  short* xn = (short*)(ws);                       // 16 MB [8192][1024] bf16
  short* win_b = (short*)(ws + 16777216);         // 6 MB  [3072][1024] bf16
  _Float16* wout_h = (_Float16*)(ws + 23068672);  // 2 MB  [1024][1024] f16
  short* qb = (short*)(ws + 25165824);            // 16 MB [BH][S][64] bf16
  short* kfrag = (short*)(ws + 41943040);         // 16 MB fragment-ordered K
  short* vfrag = (short*)(ws + 58720256);         // 16 MB fragment-ordered V
  _Float16* ob = (_Float16*)(ws + 75497472);      // 16 MB attn out [B][S][1024] f16

  k_cast_bf<<<3072, 256, 0, stream>>>(w_in, win_b, 786432);
  k_cast_f16<<<1024, 256, 0, stream>>>(w_out, wout_h, 262144);
  k_rmsnorm<<<8192, 256, 0, stream>>>(x, w_norm, xn);
  k_gemm_qkv<<<dim3(24, 64), 256, 0, stream>>>(xn, win_b, b_in, qb, kfrag, vfrag);
  k_attn<<<dim3(16, 64), 256, 0, stream>>>(qb, kfrag, vfrag, ob);
  k_gemm_out<<<dim3(8, 64), 256, 0, stream>>>(ob, wout_h, b_out, out);
}

// Round 16
// 221.083 us; speedup vs baseline: 1.1311x; 1.0463x over previous
//
#include <hip/hip_runtime.h>
#include <stdint.h>

typedef short bf16x4 __attribute__((ext_vector_type(4)));
typedef short bf16x8 __attribute__((ext_vector_type(8)));
typedef _Float16 f16x8 __attribute__((ext_vector_type(8)));
typedef float f32x4 __attribute__((ext_vector_type(4)));
typedef float f32x16 __attribute__((ext_vector_type(16)));
typedef unsigned int u32x4 __attribute__((ext_vector_type(4)));
typedef unsigned int u32x2 __attribute__((ext_vector_type(2)));

#if __has_builtin(__builtin_amdgcn_exp2f)
#define EXP2 __builtin_amdgcn_exp2f
#else
#define EXP2 exp2f
#endif

// ---------- helpers ----------
__device__ __forceinline__ short f2bf(float f) {  // RNE f32->bf16 (finite inputs)
  union { float f; uint32_t u; } v; v.f = f;
  uint32_t r = (v.u + 0x7fffu + ((v.u >> 16) & 1u)) >> 16;
  return (short)(uint16_t)r;
}

__device__ __forceinline__ unsigned cvtpk_bf16(float lo, float hi) {
  unsigned r;
  asm("v_cvt_pk_bf16_f32 %0, %1, %2" : "=v"(r) : "v"(lo), "v"(hi));
  return r;
}

// v_permlane32_swap_b32 via the BUILTIN (hazard-safe; round-5 verified).
#if __has_builtin(__builtin_amdgcn_permlane32_swap)
__device__ __forceinline__ void plane32_swap(unsigned& a, unsigned& b) {
  u32x2 r = __builtin_amdgcn_permlane32_swap(a, b, false, false);
  a = r[0]; b = r[1];
}
__device__ __forceinline__ float xhalf_sum(float x) {
  unsigned xu = __builtin_bit_cast(unsigned, x);
  u32x2 r = __builtin_amdgcn_permlane32_swap(xu, xu, false, false);
  return __builtin_bit_cast(float, r[0]) + __builtin_bit_cast(float, r[1]);
}
#else
__device__ __forceinline__ void plane32_swap(unsigned& a, unsigned& b) {
  asm("s_nop 1\n\tv_permlane32_swap_b32 %0, %1" : "+v"(a), "+v"(b));
}
__device__ __forceinline__ float xhalf_sum(float x) { return x + __shfl_xor(x, 32, 64); }
#endif

__device__ __forceinline__ float tsum16(const f32x16& s) {
  float a0 = (s[0] + s[1]) + (s[2] + s[3]);
  float a1 = (s[4] + s[5]) + (s[6] + s[7]);
  float a2 = (s[8] + s[9]) + (s[10] + s[11]);
  float a3 = (s[12] + s[13]) + (s[14] + s[15]);
  return (a0 + a1) + (a2 + a3);
}

__device__ __forceinline__ f32x16 zero16() {
  f32x16 z;
#pragma unroll
  for (int i = 0; i < 16; ++i) z[i] = 0.f;
  return z;
}

__device__ __forceinline__ void gld_lds16(const void* g, void* l) {
  __builtin_amdgcn_global_load_lds(
      (__attribute__((address_space(1))) const void*)g,
      (__attribute__((address_space(3))) void*)l, 16, 0, 0);
}

// ---------- RMSNorm + cast to bf16 ----------
__global__ __launch_bounds__(256) void k_rmsnorm(const float* __restrict__ x,
                                                 const float* __restrict__ wn,
                                                 short* __restrict__ xn) {
  const int row = blockIdx.x;      // 8192 rows
  const int t = threadIdx.x;       // 256 threads, 4 floats each
  const float4 v = reinterpret_cast<const float4*>(x + (size_t)row * 1024)[t];
  float ss = v.x * v.x + v.y * v.y + v.z * v.z + v.w * v.w;
#pragma unroll
  for (int m = 32; m >= 1; m >>= 1) ss += __shfl_xor(ss, m, 64);
  __shared__ float red[4];
  if ((t & 63) == 0) red[t >> 6] = ss;
  __syncthreads();
  const float tot = red[0] + red[1] + red[2] + red[3];
  const float rr = rsqrtf(tot * (1.0f / 1024.0f) + 1e-5f);
  const float4 g = reinterpret_cast<const float4*>(wn)[t];
  bf16x4 o;
  o[0] = f2bf(v.x * rr * g.x);
  o[1] = f2bf(v.y * rr * g.y);
  o[2] = f2bf(v.z * rr * g.z);
  o[3] = f2bf(v.w * rr * g.w);
  reinterpret_cast<bf16x4*>(xn + (size_t)row * 1024)[t] = o;
}

// ---------- casts ----------
__global__ __launch_bounds__(256) void k_cast_bf(const float* __restrict__ in,
                                                 short* __restrict__ out, int n4) {
  int i = blockIdx.x * 256 + threadIdx.x;
  if (i >= n4) return;
  float4 v = reinterpret_cast<const float4*>(in)[i];
  bf16x4 o;
  o[0] = f2bf(v.x); o[1] = f2bf(v.y); o[2] = f2bf(v.z); o[3] = f2bf(v.w);
  reinterpret_cast<bf16x4*>(out)[i] = o;
}

__global__ __launch_bounds__(256) void k_cast_f16(const float* __restrict__ in,
                                                  _Float16* __restrict__ out, int n4) {
  int i = blockIdx.x * 256 + threadIdx.x;
  if (i >= n4) return;
  float4 v = reinterpret_cast<const float4*>(in)[i];
  _Float16 o[4] = {(_Float16)v.x, (_Float16)v.y, (_Float16)v.z, (_Float16)v.w};
  reinterpret_cast<ulong1*>(out)[i] = *reinterpret_cast<ulong1*>(o);
}

// ---------- QKV GEMM (round-13 m97 structure, 128x128xBK32, T1 XCD swizzle) ----------
// Epilogue scatters Q to [BH][S][64] (scaled for exp2-softmax) and K/V
// directly into MFMA-FRAGMENT order so attention loads are lane-linear.
__global__ __launch_bounds__(256) void k_gemm_qkv(const short* __restrict__ A,
                                                  const short* __restrict__ B,
                                                  const float* __restrict__ bias,
                                                  short* __restrict__ qb,
                                                  short* __restrict__ kfrag,
                                                  short* __restrict__ vfrag) {
  __shared__ __align__(16) short As[128 * 32];
  __shared__ __align__(16) short Bs[128 * 32];
  const int t = threadIdx.x;
  // T1: XCD-aware remap (nwg = 24*64 = 1536, 1536%8==0)
  const int orig = blockIdx.y * 24 + blockIdx.x;
  const int swz = (orig & 7) * 192 + (orig >> 3);
  const long bn0 = (long)(swz % 24) * 128;
  const long bm0 = (long)(swz / 24) * 128;
  const int w = t >> 6, l = t & 63;
  const int wr = (w >> 1) * 64, wc = (w & 1) * 64;
  const int lm = l & 15, h = l >> 4;
  f32x4 acc[4][4];
#pragma unroll
  for (int i = 0; i < 4; ++i)
#pragma unroll
    for (int j = 0; j < 4; ++j) acc[i][j] = (f32x4){0.f, 0.f, 0.f, 0.f};
  const int srow = t >> 2, scol = (t & 3) * 8;
  const short* Ag = A + (bm0 + srow) * 1024 + scol;
  const short* Bg = B + (bn0 + srow) * 1024 + scol;
  short* AsP = As + t * 8;
  short* BsP = Bs + t * 8;
  for (int kt = 0; kt < 32; ++kt) {
    const int k0 = kt << 5;
    gld_lds16(Ag + k0, AsP);
    gld_lds16(Ag + k0 + 64 * 1024, AsP + 2048);
    gld_lds16(Bg + k0, BsP);
    gld_lds16(Bg + k0 + 64 * 1024, BsP + 2048);
    __syncthreads();
    bf16x8 af[4], bfr[4];
#pragma unroll
    for (int mi = 0; mi < 4; ++mi)
      af[mi] = *reinterpret_cast<const bf16x8*>(As + (wr + mi * 16 + lm) * 32 + h * 8);
#pragma unroll
    for (int ni = 0; ni < 4; ++ni)
      bfr[ni] = *reinterpret_cast<const bf16x8*>(Bs + (wc + ni * 16 + lm) * 32 + h * 8);
    __builtin_amdgcn_s_setprio(1);
#pragma unroll
    for (int mi = 0; mi < 4; ++mi)
#pragma unroll
      for (int ni = 0; ni < 4; ++ni)
        acc[mi][ni] = __builtin_amdgcn_mfma_f32_16x16x32_bf16(af[mi], bfr[ni], acc[mi][ni], 0, 0, 0);
    __builtin_amdgcn_s_setprio(0);
    __syncthreads();
  }
#pragma unroll
  for (int ni = 0; ni < 4; ++ni) {
    const int ncol = (int)bn0 + wc + ni * 16 + lm;
    const float bv = bias[ncol];
    const int which = ncol >> 10;
    const int e = ncol & 1023;
    const int hd = e >> 6, d = e & 63;
#pragma unroll
    for (int mi = 0; mi < 4; ++mi) {
#pragma unroll
      for (int r = 0; r < 4; ++r) {
        const long mrow = bm0 + wr + mi * 16 + h * 4 + r;
        const float val = acc[mi][ni][r] + bv;
        const long bh = (mrow >> 11) * 16 + hd;
        const int seq = (int)(mrow & 2047);
        if (which == 0) {
          const long off = (bh * 2048 + seq) * 64 + d;
          qb[off] = f2bf(val * 0.18033688011112042f);  // 0.125*log2(e)
        } else if (which == 1) {
          const long off = ((bh * 64 + (seq >> 5)) * 4 + (d >> 4)) * 512 +
                           ((seq & 31) | (((d >> 3) & 1) << 5)) * 8 + (d & 7);
          kfrag[off] = f2bf(val);
        } else {
          const long off = (((bh * 64 + (seq >> 5)) * 2 + (d >> 5)) * 2 +
                            ((seq >> 4) & 1)) * 512 +
                           ((d & 31) | (((seq >> 3) & 1) << 5)) * 8 + (seq & 7);
          vfrag[off] = f2bf(val);
        }
      }
    }
  }
}

// ---------- out-proj GEMM (fp16 inputs for precision, fp32 out) ----------
__global__ __launch_bounds__(256) void k_gemm_out(const _Float16* __restrict__ A,
                                                  const _Float16* __restrict__ B,
                                                  const float* __restrict__ bias,
                                                  float* __restrict__ outp) {
  __shared__ __align__(16) _Float16 As[128 * 32];
  __shared__ __align__(16) _Float16 Bs[128 * 32];
  const int t = threadIdx.x;
  // T1: nwg = 8*64 = 512, 512%8==0
  const int orig = blockIdx.y * 8 + blockIdx.x;
  const int swz = (orig & 7) * 64 + (orig >> 3);
  const long bn0 = (long)(swz % 8) * 128;
  const long bm0 = (long)(swz / 8) * 128;
  const int w = t >> 6, l = t & 63;
  const int wr = (w >> 1) * 64, wc = (w & 1) * 64;
  const int lm = l & 15, h = l >> 4;
  f32x4 acc[4][4];
#pragma unroll
  for (int i = 0; i < 4; ++i)
#pragma unroll
    for (int j = 0; j < 4; ++j) acc[i][j] = (f32x4){0.f, 0.f, 0.f, 0.f};
  const int srow = t >> 2, scol = (t & 3) * 8;
  const _Float16* Ag = A + (bm0 + srow) * 1024 + scol;
  const _Float16* Bg = B + (bn0 + srow) * 1024 + scol;
  _Float16* AsP = As + t * 8;
  _Float16* BsP = Bs + t * 8;
  for (int kt = 0; kt < 32; ++kt) {
    const int k0 = kt << 5;
    gld_lds16(Ag + k0, AsP);
    gld_lds16(Ag + k0 + 64 * 1024, AsP + 2048);
    gld_lds16(Bg + k0, BsP);
    gld_lds16(Bg + k0 + 64 * 1024, BsP + 2048);
    __syncthreads();
    f16x8 af[4], bfr[4];
#pragma unroll
    for (int mi = 0; mi < 4; ++mi)
      af[mi] = *reinterpret_cast<const f16x8*>(As + (wr + mi * 16 + lm) * 32 + h * 8);
#pragma unroll
    for (int ni = 0; ni < 4; ++ni)
      bfr[ni] = *reinterpret_cast<const f16x8*>(Bs + (wc + ni * 16 + lm) * 32 + h * 8);
    __builtin_amdgcn_s_setprio(1);
#pragma unroll
    for (int mi = 0; mi < 4; ++mi)
#pragma unroll
      for (int ni = 0; ni < 4; ++ni)
        acc[mi][ni] = __builtin_amdgcn_mfma_f32_16x16x32_f16(af[mi], bfr[ni], acc[mi][ni], 0, 0, 0);
    __builtin_amdgcn_s_setprio(0);
    __syncthreads();
  }
#pragma unroll
  for (int ni = 0; ni < 4; ++ni) {
    const int ncol = (int)bn0 + wc + ni * 16 + lm;
    const float bv = bias[ncol];
#pragma unroll
    for (int mi = 0; mi < 4; ++mi) {
#pragma unroll
      for (int r = 0; r < 4; ++r) {
        const long mrow = bm0 + wr + mi * 16 + h * 4 + r;
        outp[mrow * 1024 + ncol] = acc[mi][ni][r] + bv;
      }
    }
  }
}

// ---------- flash attention v13: shared-LDS K/V pipeline + shift softmax ----------
// Round-15 diagnosis: v12 was L2-BW-bound (each wave JIT-loads its own K/V
// copy: 21 TB/s = 60% of L2 peak) + 46us of softmax VALU. Fixes:
// (1) constant-shift softmax p=exp2(s-16): mathematically exact (shift
//     invariance; fp scale-invariant), removes max-track/rescale VALU AND the
//     serial QK->max->bcast->exp chain. Overflow needs s>143 (unreachable);
//     s<-110 underflows to 0 = true weight ~2^-120, negligible.
// (2) block-shared K/V staged to LDS with the v5-PROVEN counted-vmcnt
//     schedule (round 7, refcheck'd): 4-deep x 8KB buffers, 2 gld_lds/wave/
//     tile, loop-top vmcnt(4) + raw barrier, stage kt+3 after barrier (same
//     buffer-overwrite induction as v5; tail clamps to 63). Fragment order
//     makes BOTH gld_lds dest and ds_read lane-linear: no swizzle, conflict-
//     free. L2 traffic drops 4x (one stage serves 4 waves).
// Regs ~115 unified -> stays at 4 blocks/CU with __launch_bounds__(256,4);
// LDS 32KB/block -> 128KB/CU.
__global__ __launch_bounds__(256, 4) void k_attn(const short* __restrict__ q,
                                                 const short* __restrict__ kfrag,
                                                 const short* __restrict__ vfrag,
                                                 _Float16* __restrict__ o) {
  __shared__ __align__(16) short KV[4][4096];  // per tile: K 2048 | V 2048 shorts
  // XCD swizzle: 1024 blocks = 8 x 128; each XCD owns 8 whole heads (4MB L2)
  const int orig = blockIdx.y * 16 + blockIdx.x;
  const int work = (orig & 7) * 128 + (orig >> 3);
  const int bh = work >> 4;    // 64 heads
  const int qt = work & 15;    // 16 q-tiles of 128 rows
  const int t = threadIdx.x;
  const int w = t >> 6, l = t & 63;
  const int lq = l & 31, hh = l >> 5;
  const int qrow = qt * 128 + w * 32 + lq;

  // Q fragments: qf[db] = Q[qrow][db*16 + hh*8 .. +8]
  bf16x8 qf[4];
  const short* qp = q + ((size_t)(bh * 2048 + qrow)) * 64 + hh * 8;
#pragma unroll
  for (int db = 0; db < 4; ++db)
    qf[db] = *reinterpret_cast<const bf16x8*>(qp + db * 16);

  // staging: wave w stages granules [w*64, w*64+64) of each 2048-short tile
  const int goff = (w * 64 + l) * 8;  // shorts (lane-linear, wave-uniform base)
  const short* ksrc = kfrag + (size_t)bh * 64 * 2048 + goff;  // + kt*2048
  const short* vsrc = vfrag + (size_t)bh * 64 * 2048 + goff;

  f32x16 oa0 = zero16(), oa1 = zero16();  // dt=0,1 (d = lq, 32+lq)
  float lr = 0.f;

  // prologue: stage tiles 0..2 (6 loads in flight)
#pragma unroll
  for (int p = 0; p < 3; ++p) {
    gld_lds16(ksrc + p * 2048, &KV[p][goff]);
    gld_lds16(vsrc + p * 2048, &KV[p][2048 + goff]);
  }

#pragma unroll 1
  for (int kt = 0; kt < 64; ++kt) {
    // tile kt's 2 stages retired (kt+1/kt+2's 4 stay in flight); sync block
    asm volatile("s_waitcnt vmcnt(4)" ::: "memory");
    __builtin_amdgcn_s_barrier();
    // stage tile kt+3 into buf[(kt+3)&3] (its readers finished before
    // barrier(kt); tail clamp = re-stage of tile 63 into dead buffers)
    int kn = kt + 3; if (kn > 63) kn = 63;
    gld_lds16(ksrc + kn * 2048, &KV[(kt + 3) & 3][goff]);
    gld_lds16(vsrc + kn * 2048, &KV[(kt + 3) & 3][2048 + goff]);

    // lane-linear fragment reads (conflict-free)
    const short* kb_ = KV[kt & 3];
    bf16x8 kf[4], vf[4];
#pragma unroll
    for (int db = 0; db < 4; ++db)
      kf[db] = *reinterpret_cast<const bf16x8*>(kb_ + db * 512 + l * 8);
#pragma unroll
    for (int i = 0; i < 4; ++i)
      vf[i] = *reinterpret_cast<const bf16x8*>(kb_ + 2048 + i * 512 + l * 8);
    asm volatile("s_waitcnt lgkmcnt(0)" ::: "memory");  // frags in regs
    __builtin_amdgcn_sched_barrier(0);                  // rule #18 fence

    f32x16 s = zero16();  // 32 keys x 32 q, q-col = lq
    __builtin_amdgcn_s_setprio(1);
#pragma unroll
    for (int db = 0; db < 4; ++db)
      s = __builtin_amdgcn_mfma_f32_32x32x16_bf16(kf[db], qf[db], s, 0, 0, 0);
    __builtin_amdgcn_s_setprio(0);
    // shift softmax: p = exp2(s - 16), normalization cancels the constant
#pragma unroll
    for (int r = 0; r < 16; ++r) s[r] = EXP2(s[r] - 16.f);
    lr += tsum16(s);  // per-half-lane partial; xhalf_sum'd at the end
    __builtin_amdgcn_s_setprio(1);
#pragma unroll
    for (int kg = 0; kg < 2; ++kg) {
      const int b0 = kg * 8;
      unsigned w0 = cvtpk_bf16(s[b0 + 0], s[b0 + 1]);
      unsigned w1 = cvtpk_bf16(s[b0 + 2], s[b0 + 3]);
      unsigned w2 = cvtpk_bf16(s[b0 + 4], s[b0 + 5]);
      unsigned w3 = cvtpk_bf16(s[b0 + 6], s[b0 + 7]);
      plane32_swap(w0, w2);
      plane32_swap(w1, w3);
      u32x4 pw = {w0, w1, w2, w3};
      bf16x8 pf = *reinterpret_cast<bf16x8*>(&pw);
      oa0 = __builtin_amdgcn_mfma_f32_32x32x16_bf16(vf[0 * 2 + kg], pf, oa0, 0, 0, 0);
      oa1 = __builtin_amdgcn_mfma_f32_32x32x16_bf16(vf[1 * 2 + kg], pf, oa1, 0, 0, 0);
    }
    __builtin_amdgcn_s_setprio(0);
  }
  const float inv = 1.0f / xhalf_sum(lr);
  const int b = bh >> 4, hd = bh & 15;
  _Float16* ob = o + ((size_t)(b * 2048 + qrow)) * 1024 + hd * 64;
#pragma unroll
  for (int r2 = 0; r2 < 16; ++r2) {
    const int d0 = (r2 & 3) + 8 * (r2 >> 2) + 4 * hh;  // 32x32 C layout
    ob[d0] = (_Float16)(oa0[r2] * inv);
    ob[d0 + 32] = (_Float16)(oa1[r2] * inv);
  }
}

// ---------- launch ----------
extern "C" void kernel_launch(void* const* d_in, const int* in_sizes, int n_in,
                              void* d_out, int out_size, void* d_ws, size_t ws_size,
                              hipStream_t stream) {
  const float* x = (const float*)d_in[0];
  const float* w_in = (const float*)d_in[1];
  const float* b_in = (const float*)d_in[2];
  const float* w_norm = (const float*)d_in[3];
  const float* w_out = (const float*)d_in[4];
  const float* b_out = (const float*)d_in[5];
  float* out = (float*)d_out;
  char* ws = (char*)d_ws;
  short* xn = (short*)(ws);                       // 16 MB [8192][1024] bf16
  short* win_b = (short*)(ws + 16777216);         // 6 MB  [3072][1024] bf16
  _Float16* wout_h = (_Float16*)(ws + 23068672);  // 2 MB  [1024][1024] f16
  short* qb = (short*)(ws + 25165824);            // 16 MB [BH][S][64] bf16
  short* kfrag = (short*)(ws + 41943040);         // 16 MB fragment-ordered K
  short* vfrag = (short*)(ws + 58720256);         // 16 MB fragment-ordered V
  _Float16* ob = (_Float16*)(ws + 75497472);      // 16 MB attn out [B][S][1024] f16

  k_cast_bf<<<3072, 256, 0, stream>>>(w_in, win_b, 786432);
  k_cast_f16<<<1024, 256, 0, stream>>>(w_out, wout_h, 262144);
  k_rmsnorm<<<8192, 256, 0, stream>>>(x, w_norm, xn);
  k_gemm_qkv<<<dim3(24, 64), 256, 0, stream>>>(xn, win_b, b_in, qb, kfrag, vfrag);
  k_attn<<<dim3(16, 64), 256, 0, stream>>>(qb, kfrag, vfrag, ob);
  k_gemm_out<<<dim3(8, 64), 256, 0, stream>>>(ob, wout_h, b_out, out);
}

// Round 17
// 203.259 us; speedup vs baseline: 1.2303x; 1.0877x over previous
//
#include <hip/hip_runtime.h>
#include <stdint.h>

typedef short bf16x4 __attribute__((ext_vector_type(4)));
typedef short bf16x8 __attribute__((ext_vector_type(8)));
typedef _Float16 f16x8 __attribute__((ext_vector_type(8)));
typedef float f32x4 __attribute__((ext_vector_type(4)));
typedef float f32x16 __attribute__((ext_vector_type(16)));
typedef unsigned int u32x4 __attribute__((ext_vector_type(4)));
typedef unsigned int u32x2 __attribute__((ext_vector_type(2)));

#if __has_builtin(__builtin_amdgcn_exp2f)
#define EXP2 __builtin_amdgcn_exp2f
#else
#define EXP2 exp2f
#endif

// ---------- helpers ----------
__device__ __forceinline__ short f2bf(float f) {  // RNE f32->bf16 (finite inputs)
  union { float f; uint32_t u; } v; v.f = f;
  uint32_t r = (v.u + 0x7fffu + ((v.u >> 16) & 1u)) >> 16;
  return (short)(uint16_t)r;
}

__device__ __forceinline__ unsigned cvtpk_bf16(float lo, float hi) {
  unsigned r;
  asm("v_cvt_pk_bf16_f32 %0, %1, %2" : "=v"(r) : "v"(lo), "v"(hi));
  return r;
}

// v_permlane32_swap_b32 via the BUILTIN (hazard-safe; round-5 verified).
#if __has_builtin(__builtin_amdgcn_permlane32_swap)
__device__ __forceinline__ void plane32_swap(unsigned& a, unsigned& b) {
  u32x2 r = __builtin_amdgcn_permlane32_swap(a, b, false, false);
  a = r[0]; b = r[1];
}
__device__ __forceinline__ float xhalf_sum(float x) {
  unsigned xu = __builtin_bit_cast(unsigned, x);
  u32x2 r = __builtin_amdgcn_permlane32_swap(xu, xu, false, false);
  return __builtin_bit_cast(float, r[0]) + __builtin_bit_cast(float, r[1]);
}
#else
__device__ __forceinline__ void plane32_swap(unsigned& a, unsigned& b) {
  asm("s_nop 1\n\tv_permlane32_swap_b32 %0, %1" : "+v"(a), "+v"(b));
}
__device__ __forceinline__ float xhalf_sum(float x) { return x + __shfl_xor(x, 32, 64); }
#endif

__device__ __forceinline__ float tsum16(const f32x16& s) {
  float a0 = (s[0] + s[1]) + (s[2] + s[3]);
  float a1 = (s[4] + s[5]) + (s[6] + s[7]);
  float a2 = (s[8] + s[9]) + (s[10] + s[11]);
  float a3 = (s[12] + s[13]) + (s[14] + s[15]);
  return (a0 + a1) + (a2 + a3);
}

__device__ __forceinline__ f32x16 zero16() {
  f32x16 z;
#pragma unroll
  for (int i = 0; i < 16; ++i) z[i] = 0.f;
  return z;
}

__device__ __forceinline__ void gld_lds16(const void* g, void* l) {
  __builtin_amdgcn_global_load_lds(
      (__attribute__((address_space(1))) const void*)g,
      (__attribute__((address_space(3))) void*)l, 16, 0, 0);
}

// ---------- RMSNorm + cast to bf16 ----------
__global__ __launch_bounds__(256) void k_rmsnorm(const float* __restrict__ x,
                                                 const float* __restrict__ wn,
                                                 short* __restrict__ xn) {
  const int row = blockIdx.x;      // 8192 rows
  const int t = threadIdx.x;       // 256 threads, 4 floats each
  const float4 v = reinterpret_cast<const float4*>(x + (size_t)row * 1024)[t];
  float ss = v.x * v.x + v.y * v.y + v.z * v.z + v.w * v.w;
#pragma unroll
  for (int m = 32; m >= 1; m >>= 1) ss += __shfl_xor(ss, m, 64);
  __shared__ float red[4];
  if ((t & 63) == 0) red[t >> 6] = ss;
  __syncthreads();
  const float tot = red[0] + red[1] + red[2] + red[3];
  const float rr = rsqrtf(tot * (1.0f / 1024.0f) + 1e-5f);
  const float4 g = reinterpret_cast<const float4*>(wn)[t];
  bf16x4 o;
  o[0] = f2bf(v.x * rr * g.x);
  o[1] = f2bf(v.y * rr * g.y);
  o[2] = f2bf(v.z * rr * g.z);
  o[3] = f2bf(v.w * rr * g.w);
  reinterpret_cast<bf16x4*>(xn + (size_t)row * 1024)[t] = o;
}

// ---------- casts ----------
__global__ __launch_bounds__(256) void k_cast_bf(const float* __restrict__ in,
                                                 short* __restrict__ out, int n4) {
  int i = blockIdx.x * 256 + threadIdx.x;
  if (i >= n4) return;
  float4 v = reinterpret_cast<const float4*>(in)[i];
  bf16x4 o;
  o[0] = f2bf(v.x); o[1] = f2bf(v.y); o[2] = f2bf(v.z); o[3] = f2bf(v.w);
  reinterpret_cast<bf16x4*>(out)[i] = o;
}

__global__ __launch_bounds__(256) void k_cast_f16(const float* __restrict__ in,
                                                  _Float16* __restrict__ out, int n4) {
  int i = blockIdx.x * 256 + threadIdx.x;
  if (i >= n4) return;
  float4 v = reinterpret_cast<const float4*>(in)[i];
  _Float16 o[4] = {(_Float16)v.x, (_Float16)v.y, (_Float16)v.z, (_Float16)v.w};
  reinterpret_cast<ulong1*>(out)[i] = *reinterpret_cast<ulong1*>(o);
}

// ---------- QKV GEMM v3: 128x128, BK=64 (half the barrier drains), XOR swizzle ----------
// Round-16 profile: qkv = 98us at MfmaUtil 21% -- the 2-phase K-step loop's
// stage+drain+barrier overhead (m233: ~72% of such loops) paid 32x per block.
// BK=64 halves the K-step count (16 drains). Row stride becomes 128B, so the
// ds_read_b128 column read would be a 16-way bank conflict; fixed per rule #21
// BOTH-sides: global source granule pre-swizzled (g ^= row&7, involution,
// stays within the row's 128B span -> coalescing intact) + ds_read applies
// the same XOR. Fragments consumed per-ksub (read8 -> 16 MFMA -> read8 ->
// 16 MFMA inside one barrier pair) to hold register pressure at BK=32 levels.
// Epilogue (Q scaled / kfrag / vfrag fragment scatter) unchanged.
__global__ __launch_bounds__(256) void k_gemm_qkv(const short* __restrict__ A,
                                                  const short* __restrict__ B,
                                                  const float* __restrict__ bias,
                                                  short* __restrict__ qb,
                                                  short* __restrict__ kfrag,
                                                  short* __restrict__ vfrag) {
  __shared__ __align__(16) short As[128 * 64];  // 16KB
  __shared__ __align__(16) short Bs[128 * 64];  // 16KB
  const int t = threadIdx.x;
  // T1: XCD-aware remap (nwg = 24*64 = 1536, 1536%8==0)
  const int orig = blockIdx.y * 24 + blockIdx.x;
  const int swz = (orig & 7) * 192 + (orig >> 3);
  const long bn0 = (long)(swz % 24) * 128;
  const long bm0 = (long)(swz / 24) * 128;
  const int w = t >> 6, l = t & 63;
  const int wr = (w >> 1) * 64, wc = (w & 1) * 64;
  const int lm = l & 15, h = l >> 4;
  f32x4 acc[4][4];
#pragma unroll
  for (int i = 0; i < 4; ++i)
#pragma unroll
    for (int j = 0; j < 4; ++j) acc[i][j] = (f32x4){0.f, 0.f, 0.f, 0.f};
  // staging: 1024 granules (16B) per tile per matrix; 4 gld_lds each.
  // granule idx -> (row = idx>>3, gcol = idx&7); source gcol pre-swizzled.
  int ssrc[4], sdst[4];
#pragma unroll
  for (int i = 0; i < 4; ++i) {
    const int idx = i * 256 + t;
    const int row = idx >> 3, gc = idx & 7;
    ssrc[i] = row * 1024 + ((gc ^ (row & 7)) * 8);
    sdst[i] = idx * 8;
  }
  const short* Ag = A + bm0 * 1024;
  const short* Bg = B + bn0 * 1024;
  // swizzled LDS read offsets: row*64 + ((ks*4+h)^(row&7))*8
  int aoff[4][2], boff[4][2];
#pragma unroll
  for (int mi = 0; mi < 4; ++mi) {
#pragma unroll
    for (int ks = 0; ks < 2; ++ks) {
      const int ra = wr + mi * 16 + lm;
      aoff[mi][ks] = ra * 64 + (((ks * 4 + h) ^ (ra & 7)) * 8);
      const int rb = wc + mi * 16 + lm;
      boff[mi][ks] = rb * 64 + (((ks * 4 + h) ^ (rb & 7)) * 8);
    }
  }
  for (int kt = 0; kt < 16; ++kt) {
    const int k0 = kt * 64;
#pragma unroll
    for (int i = 0; i < 4; ++i) gld_lds16(Ag + k0 + ssrc[i], As + sdst[i]);
#pragma unroll
    for (int i = 0; i < 4; ++i) gld_lds16(Bg + k0 + ssrc[i], Bs + sdst[i]);
    __syncthreads();
    // ksub 0
    bf16x8 af[4], bfr[4];
#pragma unroll
    for (int mi = 0; mi < 4; ++mi) af[mi] = *reinterpret_cast<const bf16x8*>(As + aoff[mi][0]);
#pragma unroll
    for (int ni = 0; ni < 4; ++ni) bfr[ni] = *reinterpret_cast<const bf16x8*>(Bs + boff[ni][0]);
    __builtin_amdgcn_s_setprio(1);
#pragma unroll
    for (int mi = 0; mi < 4; ++mi)
#pragma unroll
      for (int ni = 0; ni < 4; ++ni)
        acc[mi][ni] = __builtin_amdgcn_mfma_f32_16x16x32_bf16(af[mi], bfr[ni], acc[mi][ni], 0, 0, 0);
    __builtin_amdgcn_s_setprio(0);
    // ksub 1
#pragma unroll
    for (int mi = 0; mi < 4; ++mi) af[mi] = *reinterpret_cast<const bf16x8*>(As + aoff[mi][1]);
#pragma unroll
    for (int ni = 0; ni < 4; ++ni) bfr[ni] = *reinterpret_cast<const bf16x8*>(Bs + boff[ni][1]);
    __builtin_amdgcn_s_setprio(1);
#pragma unroll
    for (int mi = 0; mi < 4; ++mi)
#pragma unroll
      for (int ni = 0; ni < 4; ++ni)
        acc[mi][ni] = __builtin_amdgcn_mfma_f32_16x16x32_bf16(af[mi], bfr[ni], acc[mi][ni], 0, 0, 0);
    __builtin_amdgcn_s_setprio(0);
    __syncthreads();
  }
#pragma unroll
  for (int ni = 0; ni < 4; ++ni) {
    const int ncol = (int)bn0 + wc + ni * 16 + lm;
    const float bv = bias[ncol];
    const int which = ncol >> 10;
    const int e = ncol & 1023;
    const int hd = e >> 6, d = e & 63;
#pragma unroll
    for (int mi = 0; mi < 4; ++mi) {
#pragma unroll
      for (int r = 0; r < 4; ++r) {
        const long mrow = bm0 + wr + mi * 16 + h * 4 + r;
        const float val = acc[mi][ni][r] + bv;
        const long bh = (mrow >> 11) * 16 + hd;
        const int seq = (int)(mrow & 2047);
        if (which == 0) {
          const long off = (bh * 2048 + seq) * 64 + d;
          qb[off] = f2bf(val * 0.18033688011112042f);  // 0.125*log2(e)
        } else if (which == 1) {
          const long off = ((bh * 64 + (seq >> 5)) * 4 + (d >> 4)) * 512 +
                           ((seq & 31) | (((d >> 3) & 1) << 5)) * 8 + (d & 7);
          kfrag[off] = f2bf(val);
        } else {
          const long off = (((bh * 64 + (seq >> 5)) * 2 + (d >> 5)) * 2 +
                            ((seq >> 4) & 1)) * 512 +
                           ((d & 31) | (((seq >> 3) & 1) << 5)) * 8 + (seq & 7);
          vfrag[off] = f2bf(val);
        }
      }
    }
  }
}

// ---------- out-proj GEMM (fp16 inputs for precision, fp32 out) ----------
__global__ __launch_bounds__(256) void k_gemm_out(const _Float16* __restrict__ A,
                                                  const _Float16* __restrict__ B,
                                                  const float* __restrict__ bias,
                                                  float* __restrict__ outp) {
  __shared__ __align__(16) _Float16 As[128 * 32];
  __shared__ __align__(16) _Float16 Bs[128 * 32];
  const int t = threadIdx.x;
  // T1: nwg = 8*64 = 512, 512%8==0
  const int orig = blockIdx.y * 8 + blockIdx.x;
  const int swz = (orig & 7) * 64 + (orig >> 3);
  const long bn0 = (long)(swz % 8) * 128;
  const long bm0 = (long)(swz / 8) * 128;
  const int w = t >> 6, l = t & 63;
  const int wr = (w >> 1) * 64, wc = (w & 1) * 64;
  const int lm = l & 15, h = l >> 4;
  f32x4 acc[4][4];
#pragma unroll
  for (int i = 0; i < 4; ++i)
#pragma unroll
    for (int j = 0; j < 4; ++j) acc[i][j] = (f32x4){0.f, 0.f, 0.f, 0.f};
  const int srow = t >> 2, scol = (t & 3) * 8;
  const _Float16* Ag = A + (bm0 + srow) * 1024 + scol;
  const _Float16* Bg = B + (bn0 + srow) * 1024 + scol;
  _Float16* AsP = As + t * 8;
  _Float16* BsP = Bs + t * 8;
  for (int kt = 0; kt < 32; ++kt) {
    const int k0 = kt << 5;
    gld_lds16(Ag + k0, AsP);
    gld_lds16(Ag + k0 + 64 * 1024, AsP + 2048);
    gld_lds16(Bg + k0, BsP);
    gld_lds16(Bg + k0 + 64 * 1024, BsP + 2048);
    __syncthreads();
    f16x8 af[4], bfr[4];
#pragma unroll
    for (int mi = 0; mi < 4; ++mi)
      af[mi] = *reinterpret_cast<const f16x8*>(As + (wr + mi * 16 + lm) * 32 + h * 8);
#pragma unroll
    for (int ni = 0; ni < 4; ++ni)
      bfr[ni] = *reinterpret_cast<const f16x8*>(Bs + (wc + ni * 16 + lm) * 32 + h * 8);
    __builtin_amdgcn_s_setprio(1);
#pragma unroll
    for (int mi = 0; mi < 4; ++mi)
#pragma unroll
      for (int ni = 0; ni < 4; ++ni)
        acc[mi][ni] = __builtin_amdgcn_mfma_f32_16x16x32_f16(af[mi], bfr[ni], acc[mi][ni], 0, 0, 0);
    __builtin_amdgcn_s_setprio(0);
    __syncthreads();
  }
#pragma unroll
  for (int ni = 0; ni < 4; ++ni) {
    const int ncol = (int)bn0 + wc + ni * 16 + lm;
    const float bv = bias[ncol];
#pragma unroll
    for (int mi = 0; mi < 4; ++mi) {
#pragma unroll
      for (int r = 0; r < 4; ++r) {
        const long mrow = bm0 + wr + mi * 16 + h * 4 + r;
        outp[mrow * 1024 + ncol] = acc[mi][ni][r] + bv;
      }
    }
  }
}

// ---------- flash attention v13 (round-16 verified, unchanged) ----------
__global__ __launch_bounds__(256, 4) void k_attn(const short* __restrict__ q,
                                                 const short* __restrict__ kfrag,
                                                 const short* __restrict__ vfrag,
                                                 _Float16* __restrict__ o) {
  __shared__ __align__(16) short KV[4][4096];  // per tile: K 2048 | V 2048 shorts
  const int orig = blockIdx.y * 16 + blockIdx.x;
  const int work = (orig & 7) * 128 + (orig >> 3);
  const int bh = work >> 4;    // 64 heads
  const int qt = work & 15;    // 16 q-tiles of 128 rows
  const int t = threadIdx.x;
  const int w = t >> 6, l = t & 63;
  const int lq = l & 31, hh = l >> 5;
  const int qrow = qt * 128 + w * 32 + lq;

  bf16x8 qf[4];
  const short* qp = q + ((size_t)(bh * 2048 + qrow)) * 64 + hh * 8;
#pragma unroll
  for (int db = 0; db < 4; ++db)
    qf[db] = *reinterpret_cast<const bf16x8*>(qp + db * 16);

  const int goff = (w * 64 + l) * 8;  // shorts (lane-linear, wave-uniform base)
  const short* ksrc = kfrag + (size_t)bh * 64 * 2048 + goff;  // + kt*2048
  const short* vsrc = vfrag + (size_t)bh * 64 * 2048 + goff;

  f32x16 oa0 = zero16(), oa1 = zero16();  // dt=0,1 (d = lq, 32+lq)
  float lr = 0.f;

#pragma unroll
  for (int p = 0; p < 3; ++p) {
    gld_lds16(ksrc + p * 2048, &KV[p][goff]);
    gld_lds16(vsrc + p * 2048, &KV[p][2048 + goff]);
  }

#pragma unroll 1
  for (int kt = 0; kt < 64; ++kt) {
    asm volatile("s_waitcnt vmcnt(4)" ::: "memory");
    __builtin_amdgcn_s_barrier();
    int kn = kt + 3; if (kn > 63) kn = 63;
    gld_lds16(ksrc + kn * 2048, &KV[(kt + 3) & 3][goff]);
    gld_lds16(vsrc + kn * 2048, &KV[(kt + 3) & 3][2048 + goff]);

    const short* kb_ = KV[kt & 3];
    bf16x8 kf[4], vf[4];
#pragma unroll
    for (int db = 0; db < 4; ++db)
      kf[db] = *reinterpret_cast<const bf16x8*>(kb_ + db * 512 + l * 8);
#pragma unroll
    for (int i = 0; i < 4; ++i)
      vf[i] = *reinterpret_cast<const bf16x8*>(kb_ + 2048 + i * 512 + l * 8);
    asm volatile("s_waitcnt lgkmcnt(0)" ::: "memory");  // frags in regs
    __builtin_amdgcn_sched_barrier(0);                  // rule #18 fence

    f32x16 s = zero16();  // 32 keys x 32 q, q-col = lq
    __builtin_amdgcn_s_setprio(1);
#pragma unroll
    for (int db = 0; db < 4; ++db)
      s = __builtin_amdgcn_mfma_f32_32x32x16_bf16(kf[db], qf[db], s, 0, 0, 0);
    __builtin_amdgcn_s_setprio(0);
    // shift softmax: p = exp2(s - 16), normalization cancels the constant
#pragma unroll
    for (int r = 0; r < 16; ++r) s[r] = EXP2(s[r] - 16.f);
    lr += tsum16(s);  // per-half-lane partial; xhalf_sum'd at the end
    __builtin_amdgcn_s_setprio(1);
#pragma unroll
    for (int kg = 0; kg < 2; ++kg) {
      const int b0 = kg * 8;
      unsigned w0 = cvtpk_bf16(s[b0 + 0], s[b0 + 1]);
      unsigned w1 = cvtpk_bf16(s[b0 + 2], s[b0 + 3]);
      unsigned w2 = cvtpk_bf16(s[b0 + 4], s[b0 + 5]);
      unsigned w3 = cvtpk_bf16(s[b0 + 6], s[b0 + 7]);
      plane32_swap(w0, w2);
      plane32_swap(w1, w3);
      u32x4 pw = {w0, w1, w2, w3};
      bf16x8 pf = *reinterpret_cast<bf16x8*>(&pw);
      oa0 = __builtin_amdgcn_mfma_f32_32x32x16_bf16(vf[0 * 2 + kg], pf, oa0, 0, 0, 0);
      oa1 = __builtin_amdgcn_mfma_f32_32x32x16_bf16(vf[1 * 2 + kg], pf, oa1, 0, 0, 0);
    }
    __builtin_amdgcn_s_setprio(0);
  }
  const float inv = 1.0f / xhalf_sum(lr);
  const int b = bh >> 4, hd = bh & 15;
  _Float16* ob = o + ((size_t)(b * 2048 + qrow)) * 1024 + hd * 64;
#pragma unroll
  for (int r2 = 0; r2 < 16; ++r2) {
    const int d0 = (r2 & 3) + 8 * (r2 >> 2) + 4 * hh;  // 32x32 C layout
    ob[d0] = (_Float16)(oa0[r2] * inv);
    ob[d0 + 32] = (_Float16)(oa1[r2] * inv);
  }
}

// ---------- launch ----------
extern "C" void kernel_launch(void* const* d_in, const int* in_sizes, int n_in,
                              void* d_out, int out_size, void* d_ws, size_t ws_size,
                              hipStream_t stream) {
  const float* x = (const float*)d_in[0];
  const float* w_in = (const float*)d_in[1];
  const float* b_in = (const float*)d_in[2];
  const float* w_norm = (const float*)d_in[3];
  const float* w_out = (const float*)d_in[4];
  const float* b_out = (const float*)d_in[5];
  float* out = (float*)d_out;
  char* ws = (char*)d_ws;
  short* xn = (short*)(ws);                       // 16 MB [8192][1024] bf16
  short* win_b = (short*)(ws + 16777216);         // 6 MB  [3072][1024] bf16
  _Float16* wout_h = (_Float16*)(ws + 23068672);  // 2 MB  [1024][1024] f16
  short* qb = (short*)(ws + 25165824);            // 16 MB [BH][S][64] bf16
  short* kfrag = (short*)(ws + 41943040);         // 16 MB fragment-ordered K
  short* vfrag = (short*)(ws + 58720256);         // 16 MB fragment-ordered V
  _Float16* ob = (_Float16*)(ws + 75497472);      // 16 MB attn out [B][S][1024] f16

  k_cast_bf<<<3072, 256, 0, stream>>>(w_in, win_b, 786432);
  k_cast_f16<<<1024, 256, 0, stream>>>(w_out, wout_h, 262144);
  k_rmsnorm<<<8192, 256, 0, stream>>>(x, w_norm, xn);
  k_gemm_qkv<<<dim3(24, 64), 256, 0, stream>>>(xn, win_b, b_in, qb, kfrag, vfrag);
  k_attn<<<dim3(16, 64), 256, 0, stream>>>(qb, kfrag, vfrag, ob);
  k_gemm_out<<<dim3(8, 64), 256, 0, stream>>>(ob, wout_h, b_out, out);
}